// Round 6
// baseline (392.672 us; speedup 1.0000x reference)
//
#include <hip/hip_runtime.h>

typedef __attribute__((ext_vector_type(8))) short bh8;
typedef __attribute__((ext_vector_type(4))) float f4;

#define DEVI static __device__ __forceinline__

DEVI unsigned short f2b(float f) {
  union { float f; unsigned u; } v; v.f = f;
  unsigned r = v.u + 0x7fffu + ((v.u >> 16) & 1u);
  return (unsigned short)(r >> 16);
}
DEVI float b2f(unsigned short h) {
  union { unsigned u; float f; } v; v.u = ((unsigned)h) << 16;
  return v.f;
}
DEVI f4 mfma16(bh8 a, bh8 b, f4 c) {
  return __builtin_amdgcn_mfma_f32_16x16x32_bf16(a, b, c, 0, 0, 0);
}
DEVI void gload_lds16(const unsigned short* g, unsigned short* l) {
  __builtin_amdgcn_global_load_lds(
      (const __attribute__((address_space(1))) void*)(g),
      (__attribute__((address_space(3))) void*)(l), 16, 0, 0);
}

// ============================ prep kernels ============================
__global__ __launch_bounds__(256) void prep_x_kern(
    const float* __restrict__ q, const float* __restrict__ k, const float* __restrict__ v,
    unsigned short* __restrict__ xq, unsigned short* __restrict__ xk, unsigned short* __restrict__ xv) {
  long i = ((long)blockIdx.x * 256 + threadIdx.x) * 4;
  if (i >= 8388608L) return;
  float4 a = *(const float4*)(q + i);
  float4 b = *(const float4*)(k + i);
  float4 c = *(const float4*)(v + i);
  union { unsigned short s[4]; uint2 u; } pa, pb, pc;
  pa.s[0] = f2b(a.x); pa.s[1] = f2b(a.y); pa.s[2] = f2b(a.z); pa.s[3] = f2b(a.w);
  pb.s[0] = f2b(b.x); pb.s[1] = f2b(b.y); pb.s[2] = f2b(b.z); pb.s[3] = f2b(b.w);
  pc.s[0] = f2b(c.x); pc.s[1] = f2b(c.y); pc.s[2] = f2b(c.z); pc.s[3] = f2b(c.w);
  *(uint2*)(xq + i) = pa.u;
  *(uint2*)(xk + i) = pb.u;
  *(uint2*)(xv + i) = pc.u;
}

__global__ __launch_bounds__(256) void prep_w_kern(
    const float* __restrict__ wq, const float* __restrict__ wk, const float* __restrict__ wv,
    const float* __restrict__ g_in_w, const float* __restrict__ g_out_w,
    const float* __restrict__ wo, const float* __restrict__ rel_k,
    unsigned short* __restrict__ Wq, unsigned short* __restrict__ Wk, unsigned short* __restrict__ Wv,
    unsigned short* __restrict__ Wgo, unsigned short* __restrict__ Wo_, unsigned short* __restrict__ Rk) {
  long i = ((long)blockIdx.x * 256 + threadIdx.x) * 4;
  if (i >= 2129984L) return;
  const float* src; unsigned short* dst; long off;
  if (i < 524288L)        { dst = Wq;  off = i; src = (i < 262144L) ? wq + i : g_in_w + (i - 262144L); }
  else if (i < 1048576L)  { long j = i - 524288L;  dst = Wk;  off = j; src = (j < 262144L) ? wk + j : g_in_w + j; }
  else if (i < 1572864L)  { long j = i - 1048576L; dst = Wv;  off = j; src = (j < 262144L) ? wv + j : g_in_w + 262144L + j; }
  else if (i < 1835008L)  { long j = i - 1572864L; dst = Wgo; off = j; src = g_out_w + j; }
  else if (i < 2097152L)  { long j = i - 1835008L; dst = Wo_; off = j; src = wo + j; }
  else                    { long j = i - 2097152L; dst = Rk;  off = j; src = rel_k + j; }
  float4 f = *(const float4*)src;
  union { unsigned short s[4]; uint2 u; } p;
  p.s[0] = f2b(f.x); p.s[1] = f2b(f.y); p.s[2] = f2b(f.z); p.s[3] = f2b(f.w);
  *(uint2*)(dst + off) = p.u;
}

// ============================ GEMM ============================
// EPI 3 now packs 4 consecutive-s bf16 into one 8B store (coalesced-ish,
// each lane fills complete 64B lines across its m-loop).
template <int NB, int EPI>
__global__ __launch_bounds__(256) void gemm_bf16_kern(
    const unsigned short* __restrict__ A, const unsigned short* __restrict__ Bw,
    const float* __restrict__ bias0, const float* __restrict__ bias1,
    const unsigned short* __restrict__ aux,
    unsigned short* __restrict__ outb, unsigned short* __restrict__ outb2,
    float* __restrict__ outf) {
  __shared__ unsigned short lsA[128 * 32];
  __shared__ unsigned short lsB[128 * 32];
  const int t = threadIdx.x;
  const int lane = t & 63, w = t >> 6;
  const int l15 = lane & 15, g8 = (lane >> 4) * 8, g4 = (lane >> 4) * 4;
  int n = blockIdx.x;
  int x = n >> 3, c = n & 7;
  const int rb = (c * 16 + (x & 15)) * 128;
  const int cb = (x >> 4) * 128;
  const int wr = (w >> 1) * 64, wc = (w & 1) * 64;
  const int e0 = t * 8, e1 = 2048 + t * 8;
  const int r0 = e0 >> 5, k0i = e0 & 31;
  const int r1 = e1 >> 5, k1i = e1 & 31;

  const unsigned short* pa0 = A + (long)(rb + r0) * 512 + k0i;
  const unsigned short* pa1 = A + (long)(rb + r1) * 512 + k1i;
  const unsigned short* pb0 = Bw + (long)(cb + r0) * 512 + k0i;
  const unsigned short* pb1 = Bw + (long)(cb + r1) * 512 + k1i;
  unsigned short* dA0 = lsA + w * 512;
  unsigned short* dA1 = lsA + 2048 + w * 512;
  unsigned short* dB0 = lsB + w * 512;
  unsigned short* dB1 = lsB + 2048 + w * 512;

  f4 acc[4][4] = {};
  for (int k0 = 0; k0 < 512; k0 += 32) {
    __syncthreads();
    gload_lds16(pa0 + k0, dA0);
    gload_lds16(pa1 + k0, dA1);
    gload_lds16(pb0 + k0, dB0);
    gload_lds16(pb1 + k0, dB1);
    __syncthreads();
    bh8 af[4], bf[4];
#pragma unroll
    for (int m = 0; m < 4; m++) af[m] = *(const bh8*)(lsA + (wr + m * 16 + l15) * 32 + g8);
#pragma unroll
    for (int nn = 0; nn < 4; nn++) bf[nn] = *(const bh8*)(lsB + (wc + nn * 16 + l15) * 32 + g8);
#pragma unroll
    for (int m = 0; m < 4; m++)
#pragma unroll
      for (int nn = 0; nn < 4; nn++)
        acc[m][nn] = mfma16(af[m], bf[nn], acc[m][nn]);
  }
#pragma unroll
  for (int m = 0; m < 4; m++) {
#pragma unroll
    for (int nn = 0; nn < 4; nn++) {
      if constexpr (EPI == 3) {
        int col = cb + wc + nn * 16 + l15;
        float bsv = (col < 512) ? bias0[col] : bias1[col - 512];
        unsigned r[4];
#pragma unroll
        for (int j = 0; j < 4; j++) {
          union { float f; unsigned u; } v; v.f = acc[m][nn][j] + bsv;
          r[j] = v.u + 0x7fffu + ((v.u >> 16) & 1u);
        }
        unsigned lo = (r[0] >> 16) | (r[1] & 0xffff0000u);
        unsigned hi = (r[2] >> 16) | (r[3] & 0xffff0000u);
        int row0 = rb + wr + m * 16 + g4;
        int bb = row0 >> 9, s = row0 & 511;
        if (col < 512) {
          int hh = col >> 6, d = col & 63;
          *(uint2*)(outb + (((long)(bb * 8 + hh) * 64 + d) << 9) + s) = make_uint2(lo, hi);
        } else {
          int c2 = col - 512, hg = c2 >> 7, dg = c2 & 127;
          *(uint2*)(outb2 + (((long)(bb * 4 + hg) * 128 + dg) << 9) + s) = make_uint2(lo, hi);
        }
      } else {
#pragma unroll
        for (int j = 0; j < 4; j++) {
          int row = rb + wr + m * 16 + g4 + j;
          int col = cb + wc + nn * 16 + l15;
          float v = acc[m][nn][j];
          if constexpr (EPI == 0) {
            v += (col < 512) ? bias0[col] : bias1[col - 512];
            outb[(long)row * (NB * 128) + col] = f2b(v);
          } else if constexpr (EPI == 1) {
            v += bias0[col];
            float cv = 0.7f * b2f(aux[(long)row * 512 + col]) + 0.3f * v;
            outb[(long)row * 512 + col] = f2b(cv);
          } else {
            v += bias0[col];
            outf[(long)row * 512 + col] = v;
          }
        }
      }
    }
  }
}

// ============================ local attention v5 ============================
// Block = 32 q-rows, 8 waves. K staged in 16KB chunks (4 x 128 rows), each
// flight hidden under gather work; V read direct from global (L2-resident,
// shared by 16 blocks). LDS ~50KB -> 3 blocks/CU.
__global__ __launch_bounds__(512, 6) void attn_local_kern(
    const unsigned short* __restrict__ Yq, const unsigned short* __restrict__ Yk,
    const unsigned short* __restrict__ Yvt, const unsigned short* __restrict__ relk,
    unsigned short* __restrict__ outL) {
  __shared__ unsigned short kv[8192];       // 16KB K chunk [128][64]
  __shared__ unsigned short buf[32 * 524];  // qrel then probs
  __shared__ float redbuf[8][32];

  const int t = threadIdx.x, lane = t & 63, w = t >> 6;
  const int l15 = lane & 15, g = lane >> 4, g8 = g * 8;
  int n = blockIdx.x;
  int bid = (n & 7) * 512 + (n >> 3);       // XCD swizzle
  const int qt = bid & 15;
  const int h = (bid >> 4) & 7;
  const int b = bid >> 7;
  const int qb = qt * 32;
  const long base = ((long)(b * 512)) * 1024 + h * 64;

  // K chunk [128 rows][64 d]: slot c holds global d-chunk c^(rr&7); dest wave-linear.
#define STAGE_K(ROFF) { \
    const int c_ = t & 7; \
    _Pragma("unroll") \
    for (int it = 0; it < 2; it++) { \
      int rr = it * 64 + (t >> 3); \
      gload_lds16(Yk + base + (long)((ROFF) + rr) * 1024 + ((c_ ^ (rr & 7)) * 8), \
                  kv + it * 4096 + w * 512); \
    } }

  // QK on staged chunk: wave w -> local row w*16+l15
#define QK(CH) { \
    int rl = w * 16 + l15; \
    bh8 k0 = *(const bh8*)(kv + rl * 64 + ((g ^ (rl & 7)) * 8)); \
    bh8 k1 = *(const bh8*)(kv + rl * 64 + (((g + 4) ^ (rl & 7)) * 8)); \
    _Pragma("unroll") \
    for (int mm = 0; mm < 2; mm++) { \
      f4 a = {}; \
      a = mfma16(qf[mm][0], k0, a); \
      a = mfma16(qf[mm][1], k1, a); \
      sc[mm][CH] = a; \
    } }

#define GATHER(CH) { \
    _Pragma("unroll") \
    for (int mm = 0; mm < 2; mm++) \
    _Pragma("unroll") \
    for (int j = 0; j < 4; j++) { \
      int lr = mm * 16 + g * 4 + j; \
      int rowb = lr * 524; \
      int idx = rowb + 256 - (qb + lr) + (CH) * 128 + w * 16 + l15; \
      idx = idx < rowb ? rowb : idx; \
      idx = idx > rowb + 512 ? rowb + 512 : idx; \
      float p = exp2f(fmaf(sc[mm][CH][j], 0.18033688011112042f, b2f(buf[idx]))); \
      sc[mm][CH][j] = p; \
      rs[mm][j] += p; \
    } }

  STAGE_K(0);

  bh8 qf[2][2];
#pragma unroll
  for (int mm = 0; mm < 2; mm++) {
    const unsigned short* qp = Yq + base + (long)(qb + mm * 16 + l15) * 1024 + g8;
    qf[mm][0] = *(const bh8*)(qp);
    qf[mm][1] = *(const bh8*)(qp + 32);
  }

  // qrel = (Q @ relk^T)*LOG2E -> buf[32][524]   (overlaps K0 staging)
  for (int tt = w; tt < 33; tt += 8) {
    int ri = tt * 16 + l15; if (ri > 512) ri = 512;
    const unsigned short* rp = relk + ri * 64 + g8;
    bh8 rf0 = *(const bh8*)(rp), rf1 = *(const bh8*)(rp + 32);
    int col = tt * 16 + l15;
#pragma unroll
    for (int mm = 0; mm < 2; mm++) {
      f4 a = {};
      a = mfma16(qf[mm][0], rf0, a);
      a = mfma16(qf[mm][1], rf1, a);
      if (col < 524) {
#pragma unroll
        for (int j = 0; j < 4; j++)
          buf[(mm * 16 + g * 4 + j) * 524 + col] = f2b(a[j] * 1.4426950408889634f);
      }
    }
  }
  __syncthreads();  // B0: K0 ready + qrel visible

  f4 sc[2][4];
  float rs[2][4] = {};

  QK(0);
  __syncthreads();  // B1: K0 reads done
  STAGE_K(128);
  GATHER(0);
  __syncthreads();  // B2: K1 ready
  QK(1);
  __syncthreads();  // B3: K1 reads done
  STAGE_K(256);
  GATHER(1);
  __syncthreads();  // B4: K2 ready
  QK(2);
  __syncthreads();  // B5: K2 reads done
  STAGE_K(384);
  GATHER(2);
  __syncthreads();  // B6: K3 ready
  QK(3);
  GATHER(3);

  // row sums -> redbuf
#pragma unroll
  for (int mm = 0; mm < 2; mm++)
#pragma unroll
    for (int j = 0; j < 4; j++) {
      int lr = mm * 16 + g * 4 + j;
      float s = rs[mm][j];
      for (int d = 1; d < 16; d <<= 1) s += __shfl_xor(s, d, 64);
      if (l15 == 0) redbuf[w][lr] = s;
    }
  __syncthreads();  // B7: all qrel reads done + redbuf visible

  // probs into buf (overwrites qrel) + rinv
#pragma unroll
  for (int mm = 0; mm < 2; mm++)
#pragma unroll
    for (int ch = 0; ch < 4; ch++) {
      int col = ch * 128 + w * 16 + l15;
#pragma unroll
      for (int j = 0; j < 4; j++)
        buf[(mm * 16 + g * 4 + j) * 524 + col] = f2b(sc[mm][ch][j]);
    }
  float rinv[2];
  {
    const int mmw = w >> 2;
#pragma unroll
    for (int j = 0; j < 4; j++) {
      int lr = mmw * 16 + g * 4 + j;
      float s = 0.f;
#pragma unroll
      for (int ww = 0; ww < 8; ww++) s += redbuf[ww][lr];
      if (j == 0) rinv[0] = __builtin_amdgcn_rcpf(s);
      // keep per-j values
      rinv[0] = (j == 0) ? rinv[0] : rinv[0];
      // (computed fully below)
    }
  }
  // recompute rinv per j properly (4 values for this wave's m-tile rows)
  float rinvj[4];
  {
    const int mmw = w >> 2;
#pragma unroll
    for (int j = 0; j < 4; j++) {
      int lr = mmw * 16 + g * 4 + j;
      float s = 0.f;
#pragma unroll
      for (int ww = 0; ww < 8; ww++) s += redbuf[ww][lr];
      rinvj[j] = __builtin_amdgcn_rcpf(s);
    }
  }
  __syncthreads();  // B8: probs visible

  // PV: wave (mmw = w>>2, dt = w&3); V direct from global (L2-resident)
  const int mmw = w >> 2, dt = w & 3;
  f4 accO = {};
  const unsigned short* vrow = Yvt + ((long)(b * 8 + h) * 64 + dt * 16 + l15) * 512;
  __builtin_amdgcn_s_setprio(1);
#pragma unroll
  for (int ks = 0; ks < 16; ks++) {
    union { uint2 u[2]; bh8 v; } pa;
    const unsigned short* pp = buf + (mmw * 16 + l15) * 524 + ks * 32 + g8;
    pa.u[0] = *(const uint2*)(pp);
    pa.u[1] = *(const uint2*)(pp + 4);
    bh8 vb = *(const bh8*)(vrow + ks * 32 + g8);
    accO = mfma16(pa.v, vb, accO);
  }
  __builtin_amdgcn_s_setprio(0);
#pragma unroll
  for (int j = 0; j < 4; j++) {
    int row = qb + mmw * 16 + g * 4 + j;
    outL[((long)(b * 512 + row)) * 512 + h * 64 + dt * 16 + l15] = f2b(accO[j] * rinvj[j]);
  }
#undef STAGE_K
#undef QK
#undef GATHER
}

// ============================ global attention v2 ============================
__global__ __launch_bounds__(512) void attn_glob_kern(
    const unsigned short* __restrict__ Yq, const unsigned short* __restrict__ Yk,
    const unsigned short* __restrict__ Yvt, unsigned short* __restrict__ outG) {
  __shared__ unsigned short buf[32 * 520];
  __shared__ float redbuf[8][32];

  const int t = threadIdx.x, lane = t & 63, w = t >> 6;
  const int l15 = lane & 15, g = lane >> 4, g8 = g * 8;
  int n = blockIdx.x;
  int bid = (n & 7) * 256 + (n >> 3);
  const int qt = bid & 15;
  const int hg = (bid >> 4) & 3;
  const int b = bid >> 6;
  const int qb = qt * 32;
  const long base = ((long)(b * 512)) * 1024 + 512 + hg * 128;

  bh8 qf[2][4];
#pragma unroll
  for (int mm = 0; mm < 2; mm++) {
    const unsigned short* qp = Yq + base + (long)(qb + mm * 16 + l15) * 1024 + g8;
#pragma unroll
    for (int ks = 0; ks < 4; ks++) qf[mm][ks] = *(const bh8*)(qp + ks * 32);
  }

  f4 sc[2][4];
  __builtin_amdgcn_s_setprio(1);
#pragma unroll
  for (int ct = 0; ct < 4; ct++) {
    int r = w * 64 + ct * 16 + l15;
    const unsigned short* kp = Yk + base + (long)r * 1024 + g8;
    bh8 kf[4];
#pragma unroll
    for (int ks = 0; ks < 4; ks++) kf[ks] = *(const bh8*)(kp + ks * 32);
#pragma unroll
    for (int mm = 0; mm < 2; mm++) {
      f4 a = {};
#pragma unroll
      for (int ks = 0; ks < 4; ks++) a = mfma16(qf[mm][ks], kf[ks], a);
      sc[mm][ct] = a;
    }
  }
  __builtin_amdgcn_s_setprio(0);

#pragma unroll
  for (int mm = 0; mm < 2; mm++) {
#pragma unroll
    for (int j = 0; j < 4; j++) {
      int lr = mm * 16 + g * 4 + j;
      float s = 0.f;
#pragma unroll
      for (int ct = 0; ct < 4; ct++) {
        float p = exp2f(sc[mm][ct][j] * 0.12751745334f);  // 1/sqrt(128)*log2(e)
        sc[mm][ct][j] = p;
        s += p;
      }
      for (int d = 1; d < 16; d <<= 1) s += __shfl_xor(s, d, 64);
      if (l15 == 0) redbuf[w][lr] = s;
    }
  }
#pragma unroll
  for (int mm = 0; mm < 2; mm++)
#pragma unroll
    for (int ct = 0; ct < 4; ct++) {
      int col = w * 64 + ct * 16 + l15;
#pragma unroll
      for (int j = 0; j < 4; j++)
        buf[(mm * 16 + g * 4 + j) * 520 + col] = f2b(sc[mm][ct][j]);
    }
  __syncthreads();  // probs + redbuf visible

  float rinv[2][4];
#pragma unroll
  for (int mm = 0; mm < 2; mm++)
#pragma unroll
    for (int j = 0; j < 4; j++) {
      int lr = mm * 16 + g * 4 + j;
      float s = 0.f;
#pragma unroll
      for (int ww = 0; ww < 8; ww++) s += redbuf[ww][lr];
      rinv[mm][j] = __builtin_amdgcn_rcpf(s);
    }

  // PV: wave w owns d-cols [w*16, +16), 2 m-tiles
  f4 accO[2] = {};
  const unsigned short* vr = Yvt + ((long)(b * 4 + hg) * 128 + w * 16 + l15) * 512;
  __builtin_amdgcn_s_setprio(1);
#pragma unroll
  for (int ks = 0; ks < 16; ks++) {
    bh8 vb = *(const bh8*)(vr + ks * 32 + g8);
#pragma unroll
    for (int mm = 0; mm < 2; mm++) {
      union { uint2 u[2]; bh8 v; } pa;
      const unsigned short* pp = buf + (mm * 16 + l15) * 520 + ks * 32 + g8;
      pa.u[0] = *(const uint2*)(pp);
      pa.u[1] = *(const uint2*)(pp + 4);
      accO[mm] = mfma16(pa.v, vb, accO[mm]);
    }
  }
  __builtin_amdgcn_s_setprio(0);
#pragma unroll
  for (int mm = 0; mm < 2; mm++)
#pragma unroll
    for (int j = 0; j < 4; j++) {
      int row = qb + mm * 16 + g * 4 + j;
      outG[((long)(b * 512 + row)) * 512 + hg * 128 + w * 16 + l15] = f2b(accO[mm][j] * rinv[mm][j]);
    }
}

// ============================ launch ============================
extern "C" void kernel_launch(void* const* d_in, const int* in_sizes, int n_in,
                              void* d_out, int out_size, void* d_ws, size_t ws_size,
                              hipStream_t stream) {
  const float* query = (const float*)d_in[0];
  const float* key   = (const float*)d_in[1];
  const float* value = (const float*)d_in[2];
  const float* wq = (const float*)d_in[3];   const float* bq = (const float*)d_in[4];
  const float* wk = (const float*)d_in[5];   const float* bk = (const float*)d_in[6];
  const float* wv = (const float*)d_in[7];   const float* bv = (const float*)d_in[8];
  const float* wo = (const float*)d_in[9];   const float* bo = (const float*)d_in[10];
  const float* rel_k = (const float*)d_in[11];
  const float* g_in_w = (const float*)d_in[12];  const float* g_in_b = (const float*)d_in[13];
  const float* g_out_w = (const float*)d_in[14]; const float* g_out_b = (const float*)d_in[15];

  unsigned short* p = (unsigned short*)d_ws;
  unsigned short* Xq = p;            p += 8388608;
  unsigned short* Xk = p;            p += 8388608;
  unsigned short* Xv = p;            p += 8388608;
  unsigned short* Yq = p;            p += 16777216;   // [16384][1024]
  unsigned short* Yk = p;            p += 16777216;
  unsigned short* Yvt_l = p;         p += 8388608;    // [b][h][64][512]
  unsigned short* Yvt_g = p;         p += 8388608;    // [b][hg][128][512]
  unsigned short* Wq = p;            p += 524288;
  unsigned short* Wk = p;            p += 524288;
  unsigned short* Wv = p;            p += 524288;
  unsigned short* Wgo = p;           p += 262144;
  unsigned short* Wo_ = p;           p += 262144;
  unsigned short* Rk = p;            p += 32832;
  unsigned short* localb = Xq;
  unsigned short* gattnb = Xk;
  unsigned short* comb   = Xv;

  prep_x_kern<<<8192, 256, 0, stream>>>(query, key, value, Xq, Xk, Xv);
  prep_w_kern<<<2081, 256, 0, stream>>>(wq, wk, wv, g_in_w, g_out_w, wo, rel_k,
                                        Wq, Wk, Wv, Wgo, Wo_, Rk);

  gemm_bf16_kern<8, 0><<<1024, 256, 0, stream>>>(Xq, Wq, bq, g_in_b, nullptr, Yq, nullptr, nullptr);
  gemm_bf16_kern<8, 0><<<1024, 256, 0, stream>>>(Xk, Wk, bk, g_in_b + 512, nullptr, Yk, nullptr, nullptr);
  gemm_bf16_kern<8, 3><<<1024, 256, 0, stream>>>(Xv, Wv, bv, g_in_b + 1024, nullptr, Yvt_l, Yvt_g, nullptr);

  attn_local_kern<<<4096, 512, 0, stream>>>(Yq, Yk, Yvt_l, Rk, localb);
  attn_glob_kern<<<2048, 512, 0, stream>>>(Yq, Yk, Yvt_g, gattnb);

  gemm_bf16_kern<4, 1><<<512, 256, 0, stream>>>(gattnb, Wgo, g_out_b, nullptr, localb, comb, nullptr, nullptr);
  gemm_bf16_kern<4, 2><<<512, 256, 0, stream>>>(comb, Wo_, bo, nullptr, nullptr, nullptr, nullptr, (float*)d_out);
}

// Round 7
// 339.730 us; speedup vs baseline: 1.1558x; 1.1558x over previous
//
#include <hip/hip_runtime.h>

typedef __attribute__((ext_vector_type(8))) short bh8;
typedef __attribute__((ext_vector_type(4))) float f4;

#define DEVI static __device__ __forceinline__

DEVI unsigned short f2b(float f) {
  union { float f; unsigned u; } v; v.f = f;
  unsigned r = v.u + 0x7fffu + ((v.u >> 16) & 1u);
  return (unsigned short)(r >> 16);
}
DEVI float b2f(unsigned short h) {
  union { unsigned u; float f; } v; v.u = ((unsigned)h) << 16;
  return v.f;
}
DEVI f4 mfma16(bh8 a, bh8 b, f4 c) {
  return __builtin_amdgcn_mfma_f32_16x16x32_bf16(a, b, c, 0, 0, 0);
}
DEVI void gload_lds16(const unsigned short* g, unsigned short* l) {
  __builtin_amdgcn_global_load_lds(
      (const __attribute__((address_space(1))) void*)(g),
      (__attribute__((address_space(3))) void*)(l), 16, 0, 0);
}

// ============================ prep kernels ============================
__global__ __launch_bounds__(256) void prep_x_kern(
    const float* __restrict__ q, const float* __restrict__ k, const float* __restrict__ v,
    unsigned short* __restrict__ xq, unsigned short* __restrict__ xk, unsigned short* __restrict__ xv) {
  long i = ((long)blockIdx.x * 256 + threadIdx.x) * 4;
  if (i >= 8388608L) return;
  float4 a = *(const float4*)(q + i);
  float4 b = *(const float4*)(k + i);
  float4 c = *(const float4*)(v + i);
  union { unsigned short s[4]; uint2 u; } pa, pb, pc;
  pa.s[0] = f2b(a.x); pa.s[1] = f2b(a.y); pa.s[2] = f2b(a.z); pa.s[3] = f2b(a.w);
  pb.s[0] = f2b(b.x); pb.s[1] = f2b(b.y); pb.s[2] = f2b(b.z); pb.s[3] = f2b(b.w);
  pc.s[0] = f2b(c.x); pc.s[1] = f2b(c.y); pc.s[2] = f2b(c.z); pc.s[3] = f2b(c.w);
  *(uint2*)(xq + i) = pa.u;
  *(uint2*)(xk + i) = pb.u;
  *(uint2*)(xv + i) = pc.u;
}

__global__ __launch_bounds__(256) void prep_w_kern(
    const float* __restrict__ wq, const float* __restrict__ wk, const float* __restrict__ wv,
    const float* __restrict__ g_in_w, const float* __restrict__ g_out_w,
    const float* __restrict__ wo, const float* __restrict__ rel_k,
    unsigned short* __restrict__ Wq, unsigned short* __restrict__ Wk, unsigned short* __restrict__ Wv,
    unsigned short* __restrict__ Wgo, unsigned short* __restrict__ Wo_, unsigned short* __restrict__ Rk) {
  long i = ((long)blockIdx.x * 256 + threadIdx.x) * 4;
  if (i >= 2129984L) return;
  const float* src; unsigned short* dst; long off;
  if (i < 524288L)        { dst = Wq;  off = i; src = (i < 262144L) ? wq + i : g_in_w + (i - 262144L); }
  else if (i < 1048576L)  { long j = i - 524288L;  dst = Wk;  off = j; src = (j < 262144L) ? wk + j : g_in_w + j; }
  else if (i < 1572864L)  { long j = i - 1048576L; dst = Wv;  off = j; src = (j < 262144L) ? wv + j : g_in_w + 262144L + j; }
  else if (i < 1835008L)  { long j = i - 1572864L; dst = Wgo; off = j; src = g_out_w + j; }
  else if (i < 2097152L)  { long j = i - 1835008L; dst = Wo_; off = j; src = wo + j; }
  else                    { long j = i - 2097152L; dst = Rk;  off = j; src = rel_k + j; }
  float4 f = *(const float4*)src;
  union { unsigned short s[4]; uint2 u; } p;
  p.s[0] = f2b(f.x); p.s[1] = f2b(f.y); p.s[2] = f2b(f.z); p.s[3] = f2b(f.w);
  *(uint2*)(dst + off) = p.u;
}

// ============================ GEMM (R2 core + EPI3 uint2 epilogue) ============================
template <int NB, int EPI>
__global__ __launch_bounds__(256) void gemm_bf16_kern(
    const unsigned short* __restrict__ A, const unsigned short* __restrict__ Bw,
    const float* __restrict__ bias0, const float* __restrict__ bias1,
    const unsigned short* __restrict__ aux,
    unsigned short* __restrict__ outb, unsigned short* __restrict__ outb2,
    float* __restrict__ outf) {
  __shared__ unsigned short lsA[128 * 32];
  __shared__ unsigned short lsB[128 * 32];
  const int t = threadIdx.x;
  const int lane = t & 63, w = t >> 6;
  const int l15 = lane & 15, g8 = (lane >> 4) * 8, g4 = (lane >> 4) * 4;
  int n = blockIdx.x;
  int x = n >> 3, c = n & 7;
  const int rb = (c * 16 + (x & 15)) * 128;
  const int cb = (x >> 4) * 128;
  const int wr = (w >> 1) * 64, wc = (w & 1) * 64;
  const int e0 = t * 8, e1 = 2048 + t * 8;
  const int r0 = e0 >> 5, k0i = e0 & 31;
  const int r1 = e1 >> 5, k1i = e1 & 31;

  const unsigned short* pa0 = A + (long)(rb + r0) * 512 + k0i;
  const unsigned short* pa1 = A + (long)(rb + r1) * 512 + k1i;
  const unsigned short* pb0 = Bw + (long)(cb + r0) * 512 + k0i;
  const unsigned short* pb1 = Bw + (long)(cb + r1) * 512 + k1i;
  unsigned short* dA0 = lsA + w * 512;
  unsigned short* dA1 = lsA + 2048 + w * 512;
  unsigned short* dB0 = lsB + w * 512;
  unsigned short* dB1 = lsB + 2048 + w * 512;

  f4 acc[4][4] = {};
  for (int k0 = 0; k0 < 512; k0 += 32) {
    __syncthreads();
    gload_lds16(pa0 + k0, dA0);
    gload_lds16(pa1 + k0, dA1);
    gload_lds16(pb0 + k0, dB0);
    gload_lds16(pb1 + k0, dB1);
    __syncthreads();
    bh8 af[4], bf[4];
#pragma unroll
    for (int m = 0; m < 4; m++) af[m] = *(const bh8*)(lsA + (wr + m * 16 + l15) * 32 + g8);
#pragma unroll
    for (int nn = 0; nn < 4; nn++) bf[nn] = *(const bh8*)(lsB + (wc + nn * 16 + l15) * 32 + g8);
#pragma unroll
    for (int m = 0; m < 4; m++)
#pragma unroll
      for (int nn = 0; nn < 4; nn++)
        acc[m][nn] = mfma16(af[m], bf[nn], acc[m][nn]);
  }
#pragma unroll
  for (int m = 0; m < 4; m++) {
#pragma unroll
    for (int nn = 0; nn < 4; nn++) {
      if constexpr (EPI == 3) {
        int col = cb + wc + nn * 16 + l15;
        float bsv = (col < 512) ? bias0[col] : bias1[col - 512];
        unsigned r[4];
#pragma unroll
        for (int j = 0; j < 4; j++) {
          union { float f; unsigned u; } v; v.f = acc[m][nn][j] + bsv;
          r[j] = v.u + 0x7fffu + ((v.u >> 16) & 1u);
        }
        unsigned lo = (r[0] >> 16) | (r[1] & 0xffff0000u);
        unsigned hi = (r[2] >> 16) | (r[3] & 0xffff0000u);
        int row0 = rb + wr + m * 16 + g4;
        int bb = row0 >> 9, s = row0 & 511;
        if (col < 512) {
          int hh = col >> 6, d = col & 63;
          *(uint2*)(outb + (((long)(bb * 8 + hh) * 64 + d) << 9) + s) = make_uint2(lo, hi);
        } else {
          int c2 = col - 512, hg = c2 >> 7, dg = c2 & 127;
          *(uint2*)(outb2 + (((long)(bb * 4 + hg) * 128 + dg) << 9) + s) = make_uint2(lo, hi);
        }
      } else {
#pragma unroll
        for (int j = 0; j < 4; j++) {
          int row = rb + wr + m * 16 + g4 + j;
          int col = cb + wc + nn * 16 + l15;
          float v = acc[m][nn][j];
          if constexpr (EPI == 0) {
            v += (col < 512) ? bias0[col] : bias1[col - 512];
            outb[(long)row * (NB * 128) + col] = f2b(v);
          } else if constexpr (EPI == 1) {
            v += bias0[col];
            float cv = 0.7f * b2f(aux[(long)row * 512 + col]) + 0.3f * v;
            outb[(long)row * 512 + col] = f2b(cv);
          } else {
            v += bias0[col];
            outf[(long)row * 512 + col] = v;
          }
        }
      }
    }
  }
}

// ============================ local attention v6 ============================
// Block = 32 q-rows, 8 waves, launch_bounds(512,4) [NO reg squeeze — R6's
// (512,6) caused 131MB scratch spill]. Double-buffered 16KB chunks:
// K as 4x[128][64], then V as 4x[64][128]; each DMA flight hides under the
// previous chunk's QK+GATHER (or PV) phase. LDS 66KB -> 2 blocks/CU.
__global__ __launch_bounds__(512, 4) void attn_local_kern(
    const unsigned short* __restrict__ Yq, const unsigned short* __restrict__ Yk,
    const unsigned short* __restrict__ Yvt, const unsigned short* __restrict__ relk,
    unsigned short* __restrict__ outL) {
  __shared__ unsigned short kv[2][8192];    // 2 x 16KB chunk
  __shared__ unsigned short buf[32 * 524];  // qrel then probs
  __shared__ float redbuf[8][32];

  const int t = threadIdx.x, lane = t & 63, w = t >> 6;
  const int l15 = lane & 15, g = lane >> 4, g8 = g * 8;
  int n = blockIdx.x;
  int bid = (n & 7) * 512 + (n >> 3);       // XCD swizzle
  const int qt = bid & 15;
  const int h = (bid >> 4) & 7;
  const int b = bid >> 7;
  const int qb = qt * 32;
  const long base = ((long)(b * 512)) * 1024 + h * 64;
  const long vbase = ((long)(b * 8 + h)) * 64 * 512;

  // K chunk [128 rows][64 d]: slot chunk c_ holds global d-chunk c_^(rr&7).
#define STAGE_K(ROFF, BUF) { \
    const int c_ = t & 7; \
    _Pragma("unroll") \
    for (int it = 0; it < 2; it++) { \
      int rr = it * 64 + (t >> 3); \
      gload_lds16(Yk + base + (long)((ROFF) + rr) * 1024 + ((c_ ^ (rr & 7)) * 8), \
                  kv[BUF] + it * 4096 + w * 512); \
    } }
  // V chunk [64 d][128 k]: slot chunk c_ (of 16) holds global k-chunk c_^(dd&15).
#define STAGE_V(COFF, BUF) { \
    const int c_ = t & 15; \
    _Pragma("unroll") \
    for (int it = 0; it < 2; it++) { \
      int dd_ = it * 32 + (t >> 4); \
      gload_lds16(Yvt + vbase + (long)dd_ * 512 + (COFF) + ((c_ ^ (dd_ & 15)) * 8), \
                  kv[BUF] + it * 4096 + w * 512); \
    } }

#define QK(CH) { \
    int rl = w * 16 + l15; \
    const unsigned short* kb_ = kv[(CH) & 1]; \
    bh8 k0 = *(const bh8*)(kb_ + rl * 64 + ((g ^ (rl & 7)) * 8)); \
    bh8 k1 = *(const bh8*)(kb_ + rl * 64 + (((g + 4) ^ (rl & 7)) * 8)); \
    _Pragma("unroll") \
    for (int mm = 0; mm < 2; mm++) { \
      f4 a = {}; \
      a = mfma16(qf[mm][0], k0, a); \
      a = mfma16(qf[mm][1], k1, a); \
      sc[mm][CH] = a; \
    } }

#define GATHER(CH) { \
    _Pragma("unroll") \
    for (int mm = 0; mm < 2; mm++) \
    _Pragma("unroll") \
    for (int j = 0; j < 4; j++) { \
      int lr = mm * 16 + g * 4 + j; \
      int rowb = lr * 524; \
      int idx = rowb + 256 - (qb + lr) + (CH) * 128 + w * 16 + l15; \
      idx = idx < rowb ? rowb : idx; \
      idx = idx > rowb + 512 ? rowb + 512 : idx; \
      float p = exp2f(fmaf(sc[mm][CH][j], 0.18033688011112042f, b2f(buf[idx]))); \
      sc[mm][CH][j] = p; \
      rs[mm][j] += p; \
    } }

  STAGE_K(0, 0);

  bh8 qf[2][2];
#pragma unroll
  for (int mm = 0; mm < 2; mm++) {
    const unsigned short* qp = Yq + base + (long)(qb + mm * 16 + l15) * 1024 + g8;
    qf[mm][0] = *(const bh8*)(qp);
    qf[mm][1] = *(const bh8*)(qp + 32);
  }

  // qrel = (Q @ relk^T)*LOG2E -> buf[32][524]   (overlaps K0 flight)
  for (int tt = w; tt < 33; tt += 8) {
    int ri = tt * 16 + l15; if (ri > 512) ri = 512;
    const unsigned short* rp = relk + ri * 64 + g8;
    bh8 rf0 = *(const bh8*)(rp), rf1 = *(const bh8*)(rp + 32);
    int col = tt * 16 + l15;
#pragma unroll
    for (int mm = 0; mm < 2; mm++) {
      f4 a = {};
      a = mfma16(qf[mm][0], rf0, a);
      a = mfma16(qf[mm][1], rf1, a);
      if (col < 524) {
#pragma unroll
        for (int j = 0; j < 4; j++)
          buf[(mm * 16 + g * 4 + j) * 524 + col] = f2b(a[j] * 1.4426950408889634f);
      }
    }
  }
  __syncthreads();  // B0: K0 ready + qrel visible

  f4 sc[2][4];
  float rs[2][4] = {};

  // K pipeline: stage next chunk (alt buffer) under QK+GATHER of current.
#pragma unroll
  for (int c = 0; c < 4; c++) {
    if (c < 3) { STAGE_K((c + 1) * 128, (c + 1) & 1); }
    else       { STAGE_V(0, 0); }        // kv[0] free since chunk-2 barrier
    __builtin_amdgcn_s_setprio(1);
    QK(c);
    __builtin_amdgcn_s_setprio(0);
    GATHER(c);
    __syncthreads();  // next chunk staged + current reads done
  }

  // row sums -> redbuf; probs into buf (qrel dead now)
#pragma unroll
  for (int mm = 0; mm < 2; mm++)
#pragma unroll
    for (int j = 0; j < 4; j++) {
      int lr = mm * 16 + g * 4 + j;
      float s = rs[mm][j];
      for (int d = 1; d < 16; d <<= 1) s += __shfl_xor(s, d, 64);
      if (l15 == 0) redbuf[w][lr] = s;
    }
#pragma unroll
  for (int mm = 0; mm < 2; mm++)
#pragma unroll
    for (int ch = 0; ch < 4; ch++) {
      int col = ch * 128 + w * 16 + l15;
#pragma unroll
      for (int j = 0; j < 4; j++)
        buf[(mm * 16 + g * 4 + j) * 524 + col] = f2b(sc[mm][ch][j]);
    }
  __syncthreads();  // B5: probs + redbuf visible (V0 staged too)

  const int mmw = w >> 2, dt = w & 3;
  const int dd = dt * 16 + l15;
  float rinvj[4];
#pragma unroll
  for (int j = 0; j < 4; j++) {
    int lr = mmw * 16 + g * 4 + j;
    float s = 0.f;
#pragma unroll
    for (int ww = 0; ww < 8; ww++) s += redbuf[ww][lr];
    rinvj[j] = __builtin_amdgcn_rcpf(s);
  }

  // V pipeline: PV on chunk d while chunk d+1 in flight.
  f4 accO = {};
#pragma unroll
  for (int d = 0; d < 4; d++) {
    if (d < 3) { STAGE_V((d + 1) * 128, (d + 1) & 1); }
    const unsigned short* vb_ = kv[d & 1];
    __builtin_amdgcn_s_setprio(1);
#pragma unroll
    for (int ks2 = 0; ks2 < 4; ks2++) {
      union { uint2 u[2]; bh8 v; } pa;
      const unsigned short* pp = buf + (mmw * 16 + l15) * 524 + (d * 4 + ks2) * 32 + g8;
      pa.u[0] = *(const uint2*)(pp);
      pa.u[1] = *(const uint2*)(pp + 4);
      bh8 vv = *(const bh8*)(vb_ + dd * 128 + (((ks2 * 4 + g) ^ (dd & 15)) * 8));
      accO = mfma16(pa.v, vv, accO);
    }
    __builtin_amdgcn_s_setprio(0);
    if (d < 3) __syncthreads();
  }
#pragma unroll
  for (int j = 0; j < 4; j++) {
    int row = qb + mmw * 16 + g * 4 + j;
    outL[((long)(b * 512 + row)) * 512 + h * 64 + dt * 16 + l15] = f2b(accO[j] * rinvj[j]);
  }
#undef STAGE_K
#undef STAGE_V
#undef QK
#undef GATHER
}

// ============================ global attention v2 ============================
__global__ __launch_bounds__(512) void attn_glob_kern(
    const unsigned short* __restrict__ Yq, const unsigned short* __restrict__ Yk,
    const unsigned short* __restrict__ Yvt, unsigned short* __restrict__ outG) {
  __shared__ unsigned short buf[32 * 520];
  __shared__ float redbuf[8][32];

  const int t = threadIdx.x, lane = t & 63, w = t >> 6;
  const int l15 = lane & 15, g = lane >> 4, g8 = g * 8;
  int n = blockIdx.x;
  int bid = (n & 7) * 256 + (n >> 3);
  const int qt = bid & 15;
  const int hg = (bid >> 4) & 3;
  const int b = bid >> 6;
  const int qb = qt * 32;
  const long base = ((long)(b * 512)) * 1024 + 512 + hg * 128;

  bh8 qf[2][4];
#pragma unroll
  for (int mm = 0; mm < 2; mm++) {
    const unsigned short* qp = Yq + base + (long)(qb + mm * 16 + l15) * 1024 + g8;
#pragma unroll
    for (int ks = 0; ks < 4; ks++) qf[mm][ks] = *(const bh8*)(qp + ks * 32);
  }

  f4 sc[2][4];
  __builtin_amdgcn_s_setprio(1);
#pragma unroll
  for (int ct = 0; ct < 4; ct++) {
    int r = w * 64 + ct * 16 + l15;
    const unsigned short* kp = Yk + base + (long)r * 1024 + g8;
    bh8 kf[4];
#pragma unroll
    for (int ks = 0; ks < 4; ks++) kf[ks] = *(const bh8*)(kp + ks * 32);
#pragma unroll
    for (int mm = 0; mm < 2; mm++) {
      f4 a = {};
#pragma unroll
      for (int ks = 0; ks < 4; ks++) a = mfma16(qf[mm][ks], kf[ks], a);
      sc[mm][ct] = a;
    }
  }
  __builtin_amdgcn_s_setprio(0);

#pragma unroll
  for (int mm = 0; mm < 2; mm++) {
#pragma unroll
    for (int j = 0; j < 4; j++) {
      int lr = mm * 16 + g * 4 + j;
      float s = 0.f;
#pragma unroll
      for (int ct = 0; ct < 4; ct++) {
        float p = exp2f(sc[mm][ct][j] * 0.12751745334f);  // 1/sqrt(128)*log2(e)
        sc[mm][ct][j] = p;
        s += p;
      }
      for (int d = 1; d < 16; d <<= 1) s += __shfl_xor(s, d, 64);
      if (l15 == 0) redbuf[w][lr] = s;
    }
  }
#pragma unroll
  for (int mm = 0; mm < 2; mm++)
#pragma unroll
    for (int ct = 0; ct < 4; ct++) {
      int col = w * 64 + ct * 16 + l15;
#pragma unroll
      for (int j = 0; j < 4; j++)
        buf[(mm * 16 + g * 4 + j) * 520 + col] = f2b(sc[mm][ct][j]);
    }
  __syncthreads();  // probs + redbuf visible

  float rinv[2][4];
#pragma unroll
  for (int mm = 0; mm < 2; mm++)
#pragma unroll
    for (int j = 0; j < 4; j++) {
      int lr = mm * 16 + g * 4 + j;
      float s = 0.f;
#pragma unroll
      for (int ww = 0; ww < 8; ww++) s += redbuf[ww][lr];
      rinv[mm][j] = __builtin_amdgcn_rcpf(s);
    }

  // PV: wave w owns d-cols [w*16, +16), 2 m-tiles
  f4 accO[2] = {};
  const unsigned short* vr = Yvt + ((long)(b * 4 + hg) * 128 + w * 16 + l15) * 512;
  __builtin_amdgcn_s_setprio(1);
#pragma unroll
  for (int ks = 0; ks < 16; ks++) {
    bh8 vb = *(const bh8*)(vr + ks * 32 + g8);
#pragma unroll
    for (int mm = 0; mm < 2; mm++) {
      union { uint2 u[2]; bh8 v; } pa;
      const unsigned short* pp = buf + (mm * 16 + l15) * 520 + ks * 32 + g8;
      pa.u[0] = *(const uint2*)(pp);
      pa.u[1] = *(const uint2*)(pp + 4);
      accO[mm] = mfma16(pa.v, vb, accO[mm]);
    }
  }
  __builtin_amdgcn_s_setprio(0);
#pragma unroll
  for (int mm = 0; mm < 2; mm++)
#pragma unroll
    for (int j = 0; j < 4; j++) {
      int row = qb + mm * 16 + g * 4 + j;
      outG[((long)(b * 512 + row)) * 512 + hg * 128 + w * 16 + l15] = f2b(accO[mm][j] * rinv[mm][j]);
    }
}

// ============================ launch ============================
extern "C" void kernel_launch(void* const* d_in, const int* in_sizes, int n_in,
                              void* d_out, int out_size, void* d_ws, size_t ws_size,
                              hipStream_t stream) {
  const float* query = (const float*)d_in[0];
  const float* key   = (const float*)d_in[1];
  const float* value = (const float*)d_in[2];
  const float* wq = (const float*)d_in[3];   const float* bq = (const float*)d_in[4];
  const float* wk = (const float*)d_in[5];   const float* bk = (const float*)d_in[6];
  const float* wv = (const float*)d_in[7];   const float* bv = (const float*)d_in[8];
  const float* wo = (const float*)d_in[9];   const float* bo = (const float*)d_in[10];
  const float* rel_k = (const float*)d_in[11];
  const float* g_in_w = (const float*)d_in[12];  const float* g_in_b = (const float*)d_in[13];
  const float* g_out_w = (const float*)d_in[14]; const float* g_out_b = (const float*)d_in[15];

  unsigned short* p = (unsigned short*)d_ws;
  unsigned short* Xq = p;            p += 8388608;
  unsigned short* Xk = p;            p += 8388608;
  unsigned short* Xv = p;            p += 8388608;
  unsigned short* Yq = p;            p += 16777216;   // [16384][1024]
  unsigned short* Yk = p;            p += 16777216;
  unsigned short* Yvt_l = p;         p += 8388608;    // [b][h][64][512]
  unsigned short* Yvt_g = p;         p += 8388608;    // [b][hg][128][512]
  unsigned short* Wq = p;            p += 524288;
  unsigned short* Wk = p;            p += 524288;
  unsigned short* Wv = p;            p += 524288;
  unsigned short* Wgo = p;           p += 262144;
  unsigned short* Wo_ = p;           p += 262144;
  unsigned short* Rk = p;            p += 32832;
  unsigned short* localb = Xq;
  unsigned short* gattnb = Xk;
  unsigned short* comb   = Xv;

  prep_x_kern<<<8192, 256, 0, stream>>>(query, key, value, Xq, Xk, Xv);
  prep_w_kern<<<2081, 256, 0, stream>>>(wq, wk, wv, g_in_w, g_out_w, wo, rel_k,
                                        Wq, Wk, Wv, Wgo, Wo_, Rk);

  gemm_bf16_kern<8, 0><<<1024, 256, 0, stream>>>(Xq, Wq, bq, g_in_b, nullptr, Yq, nullptr, nullptr);
  gemm_bf16_kern<8, 0><<<1024, 256, 0, stream>>>(Xk, Wk, bk, g_in_b + 512, nullptr, Yk, nullptr, nullptr);
  gemm_bf16_kern<8, 3><<<1024, 256, 0, stream>>>(Xv, Wv, bv, g_in_b + 1024, nullptr, Yvt_l, Yvt_g, nullptr);

  attn_local_kern<<<4096, 512, 0, stream>>>(Yq, Yk, Yvt_l, Rk, localb);
  attn_glob_kern<<<2048, 512, 0, stream>>>(Yq, Yk, Yvt_g, gattnb);

  gemm_bf16_kern<4, 1><<<512, 256, 0, stream>>>(gattnb, Wgo, g_out_b, nullptr, localb, comb, nullptr, nullptr);
  gemm_bf16_kern<4, 2><<<512, 256, 0, stream>>>(comb, Wo_, bo, nullptr, nullptr, nullptr, nullptr, (float*)d_out);
}